// Round 15
// baseline (1835.328 us; speedup 1.0000x reference)
//
#include <hip/hip_runtime.h>
#include <hip/hip_bf16.h>
#include <stdint.h>

#define T_SEQ 128
#define NBATCH 32
#define EMBED 512
#define HID 1024
#define NVOCAB 32000
#define NBLK 256   // recurrence worker blocks

typedef float f32x4 __attribute__((ext_vector_type(4)));
typedef _Float16 f16x8 __attribute__((ext_vector_type(8)));

__device__ __forceinline__ unsigned short f2h(float f) {
  _Float16 h = (_Float16)f;
  return __builtin_bit_cast(unsigned short, h);
}
__device__ __forceinline__ float sigm(float x) {
  return 1.0f / (1.0f + __expf(-x));
}
__device__ __forceinline__ float tanh_fast(float x) {
  return 2.0f / (1.0f + __expf(-2.0f * x)) - 1.0f;
}
__device__ __forceinline__ unsigned umin4(unsigned a, unsigned b, unsigned c, unsigned d) {
  unsigned x = a < b ? a : b;
  unsigned y = c < d ? c : d;
  return x < y ? x : y;
}

// ---------------- zero the sync flags (512 uints) ----------------
__global__ void k_zero(unsigned int* __restrict__ p, int n) {
  int i = blockIdx.x * blockDim.x + threadIdx.x;
  if (i < n) p[i] = 0;
}

// ---------------- f32 -> f16 convert (vectorized, grid-stride) ----------------
__global__ void k_f32_to_f16(const float4* __restrict__ in,
                             ushort4* __restrict__ out, int n4) {
  int i = blockIdx.x * blockDim.x + threadIdx.x;
  int stride = gridDim.x * blockDim.x;
  for (; i < n4; i += stride) {
    float4 v = in[i];
    ushort4 o;
    o.x = f2h(v.x); o.y = f2h(v.y); o.z = f2h(v.z); o.w = f2h(v.w);
    out[i] = o;
  }
}

// ------------- embedding gather -> A0 f16 [4096][512], row m = t*32+b -------------
__global__ void k_embed(const int* __restrict__ tok, const float* __restrict__ table,
                        ushort4* __restrict__ A0) {
  int tid = blockIdx.x * 256 + threadIdx.x;   // 4096*128 threads total
  int m = tid >> 7, kq = tid & 127;
  int b = m & 31, t = m >> 5;
  int tk = tok[b * T_SEQ + t];
  float4 v = *(const float4*)(table + (size_t)tk * EMBED + kq * 4);
  ushort4 o;
  o.x = f2h(v.x); o.y = f2h(v.y); o.z = f2h(v.z); o.w = f2h(v.w);
  A0[tid] = o;
}

// ============ 256^2 8-phase f16 GEMM template: C = A[M,K] x B[N,K]^T (+bias) ============
// Round-11 proven structure. Templated on LK (=K), GNT (=K/64), PERM (logits row perm).
template<int LKv, int GNTv, bool PERM>
__global__ __launch_bounds__(512, 2) void k_gemm256(
    const short* __restrict__ A,    // [M][LKv] f16
    const short* __restrict__ B,    // [N][LKv] f16
    float* __restrict__ C,          // [M][N] f32
    const float* __restrict__ bias, // [N]
    int N)                          // C stride
{
  __shared__ __align__(16) short As[2][256 * 64];   // 64 KB
  __shared__ __align__(16) short Bs[2][256 * 64];   // 64 KB

  const int tid = threadIdx.x;
  const int l = tid & 63, wid = tid >> 6;
  const int wm = wid >> 2, wn = wid & 3;
  const int l15 = l & 15, lkg = l >> 4;
  const int bm = blockIdx.x * 256, bn = blockIdx.y * 256;

  f32x4 acc[8][4] = {};

  auto stage_half = [&](int kt, int op, int half) {
    const short* G = op ? B : A;
    const int base_row = (op ? bn : bm) + half * 128;
    char* L = (char*)(op ? Bs[kt & 1] : As[kt & 1]) + half * 128 * 64 * 2;
#pragma unroll
    for (int p = 0; p < 2; ++p) {
      int chunk = p * 512 + tid;           // 16B chunk in half-tile
      int Lbyte = chunk * 16;
      int r = Lbyte >> 7;                  // row (128B per row)
      int cb = Lbyte & 127;
      int scb = cb ^ ((r & 7) << 4);       // swizzled source col-byte (involution)
      const char* src = (const char*)&G[(size_t)(base_row + r) * LKv + kt * 64] + scb;
      char* dst = L + (p * 512 + wid * 64) * 16;   // wave-uniform; HW adds lane*16
      __builtin_amdgcn_global_load_lds(
          (const __attribute__((address_space(1))) void*)src,
          (__attribute__((address_space(3))) void*)dst, 16, 0, 0);
    }
  };

  // ---- prologue: stage A(t0), B(t0), A(t1); allow A(t1) in flight ----
  stage_half(0, 0, 0); stage_half(0, 0, 1);
  stage_half(0, 1, 0); stage_half(0, 1, 1);
  stage_half(1, 0, 0); stage_half(1, 0, 1);
  asm volatile("s_waitcnt vmcnt(4)" ::: "memory");
  __builtin_amdgcn_sched_barrier(0);
  __builtin_amdgcn_s_barrier();
  __builtin_amdgcn_sched_barrier(0);

  for (int kt = 0; kt < GNTv; ++kt) {
    const char* bufA = (const char*)As[kt & 1];
    const char* bufB = (const char*)Bs[kt & 1];
    f16x8 afr[8][2];
    f16x8 bfr[2][2];

#define RD_A(mi_, ks_) \
    (*(const f16x8*)(bufA + ((wm * 128 + (mi_) * 16 + l15) * 128 + \
        (((ks_) * 64 + lkg * 16) ^ (((wm * 128 + (mi_) * 16 + l15) & 7) << 4)))))
#define RD_B(ni_, ks_) \
    (*(const f16x8*)(bufB + ((wn * 64 + (ni_) * 16 + l15) * 128 + \
        (((ks_) * 64 + lkg * 16) ^ (((wn * 64 + (ni_) * 16 + l15) & 7) << 4)))))

#define MFMA_QUAD(MI0, NI0) \
    __builtin_amdgcn_s_setprio(1); \
    _Pragma("unroll") \
    for (int ks = 0; ks < 2; ++ks) \
      _Pragma("unroll") \
      for (int i = 0; i < 4; ++i) \
        _Pragma("unroll") \
        for (int j = 0; j < 2; ++j) \
          acc[(MI0) + i][(NI0) + j] = __builtin_amdgcn_mfma_f32_16x16x32_f16( \
              afr[(MI0) + i][ks], bfr[j][ks], acc[(MI0) + i][(NI0) + j], 0, 0, 0); \
    __builtin_amdgcn_s_setprio(0);

#define PHASE_BARS() \
    __builtin_amdgcn_s_barrier(); __builtin_amdgcn_sched_barrier(0);

    // ---- q0: read A(mi0-3) + B(ni0-1); stage B(kt+1, half0); MFMA quad (0,0) ----
#pragma unroll
    for (int i = 0; i < 4; ++i) { afr[i][0] = RD_A(i, 0); afr[i][1] = RD_A(i, 1); }
#pragma unroll
    for (int j = 0; j < 2; ++j) { bfr[j][0] = RD_B(j, 0); bfr[j][1] = RD_B(j, 1); }
    if (kt + 1 < GNTv) stage_half(kt + 1, 1, 0);
    PHASE_BARS();
    MFMA_QUAD(0, 0);
    PHASE_BARS();

    // ---- q1: read A(mi4-7); stage B(kt+1, half1); MFMA quad (4,0) ----
#pragma unroll
    for (int i = 0; i < 4; ++i) { afr[4 + i][0] = RD_A(4 + i, 0); afr[4 + i][1] = RD_A(4 + i, 1); }
    if (kt + 1 < GNTv) stage_half(kt + 1, 1, 1);
    PHASE_BARS();
    MFMA_QUAD(4, 0);
    PHASE_BARS();

    // ---- q2: read B(ni2-3); stage A(kt+2, half0); MFMA quad (0,2) ----
#pragma unroll
    for (int j = 0; j < 2; ++j) { bfr[j][0] = RD_B(2 + j, 0); bfr[j][1] = RD_B(2 + j, 1); }
    if (kt + 2 < GNTv) stage_half(kt + 2, 0, 0);
    PHASE_BARS();
    MFMA_QUAD(0, 2);
    PHASE_BARS();

    // ---- q3: stage A(kt+2, half1); MFMA quad (4,2) ----
    if (kt + 2 < GNTv) stage_half(kt + 2, 0, 1);
    PHASE_BARS();
    MFMA_QUAD(4, 2);
    PHASE_BARS();

    // ---- tile boundary: counted vmcnt (A(kt+2) halves may stay in flight) ----
    if (kt + 1 < GNTv) {
      if (kt + 2 < GNTv) {
        asm volatile("s_waitcnt vmcnt(4)" ::: "memory");
      } else {
        asm volatile("s_waitcnt vmcnt(0)" ::: "memory");
      }
      __builtin_amdgcn_sched_barrier(0);
      __builtin_amdgcn_s_barrier();
      __builtin_amdgcn_sched_barrier(0);
    }
#undef RD_A
#undef RD_B
#undef MFMA_QUAD
#undef PHASE_BARS
  }

  // ---- epilogue: (optionally permuted) rows + bias ----
  const int lr = lkg * 4;
#pragma unroll
  for (int mi = 0; mi < 8; ++mi) {
#pragma unroll
    for (int ni = 0; ni < 4; ++ni) {
      int col = bn + wn * 64 + ni * 16 + l15;
      float bv = bias[col];
#pragma unroll
      for (int j = 0; j < 4; ++j) {
        int row = bm + wm * 128 + mi * 16 + lr + j;
        int orow = PERM ? ((row & 31) * T_SEQ + (row >> 5)) : row;
        C[(size_t)orow * N + col] = acc[mi][ni][j] + bv;
      }
    }
  }
}

// ---------------- fused 2-layer GRU recurrence (r4 protocol + EARLY per-role-pair publish) ----------------
// 256 blocks x 384 threads. Block owns j in [4*bid,4*bid+4); wave w: role=w>>1
// (0: W_hh0 @ s, 1: W_ih1 @ s-1, 2: W_hh1 @ s-2), nt=w&1 (batch half).
// SINGLE CHANGE vs r4 (r10's confound isolated): flags publish EARLY via LDS-atomic
// pairing — each role-0 wave drains its own sc1 h-stores (vmcnt 0), lane0 bumps a
// monotonic LDS counter; the SECOND arrival publishes flg0[bid]=s+1 (same flag
// address/value/poll as r4, ~2us earlier, decoupled from roles 1/2 + bottom barrier).
// Role-2 pair -> flg1 identically. tid0's post-barrier publishes removed. Ordering:
// both waves' h-stores are at L3 (vmcnt-drained) before their LDS token; publisher
// issues the flag only after observing both tokens.
__global__ __launch_bounds__(384, 2) void k_gru_fused(
    const float* __restrict__ gi0,    // [128][32][3072] (includes b_ih0)
    const float* __restrict__ Whh0,   // [3072][1024]
    const float* __restrict__ bhh0,   // [3072]
    const float* __restrict__ Wih1,   // [3072][1024]
    const float* __restrict__ bih1,   // [3072]
    const float* __restrict__ Whh1,   // [3072][1024]
    const float* __restrict__ bhh1,   // [3072]
    const _Float16* __restrict__ h0i, // [32][1024]
    const _Float16* __restrict__ h1i, // [32][1024]
    _Float16* __restrict__ ys0f,      // [128][32][1024]
    _Float16* __restrict__ ys1f,      // [128][32][1024]
    unsigned int* flg0,               // [256]
    unsigned int* flg1)               // [256]
{
  __shared__ float bufIH[2][3][2][64];  // [parity][gate][nt][lane]
  __shared__ unsigned cnt0, cnt1;       // monotonic arrival counters (2 per iter)

  const int tid = threadIdx.x;
  const int l = tid & 63;
  const int w = tid >> 6;
  const int role = w >> 1, nt = w & 1;
  const int bid = blockIdx.x;
  const int j0 = bid * 4;

  const int row16 = l & 15;
  const int jjr = row16 >> 2, gate = row16 & 3;
  const int koct = l >> 4;

  const int b_out = nt * 16 + (l & 15);
  const int j_out = j0 + (l >> 4);
  const int jj_even = (((l >> 4) & 1) == 0);

  if (tid == 0) { cnt0 = 0u; cnt1 = 0u; }   // ordered by the first top barrier

  const float* Wsrc = (role == 0) ? Whh0 : ((role == 1) ? Wih1 : Whh1);
  f16x8 af[32];
  if (gate < 3) {
    const float* wrow = Wsrc + (size_t)(gate * HID + j0 + jjr) * HID;
#pragma unroll
    for (int c = 0; c < 32; ++c) {
      float4 p0 = *(const float4*)(wrow + c * 32 + koct * 8);
      float4 p1 = *(const float4*)(wrow + c * 32 + koct * 8 + 4);
      f16x8 v = { (_Float16)p0.x, (_Float16)p0.y, (_Float16)p0.z, (_Float16)p0.w,
                  (_Float16)p1.x, (_Float16)p1.y, (_Float16)p1.z, (_Float16)p1.w };
      af[c] = v;
    }
  } else {
#pragma unroll
    for (int c = 0; c < 32; ++c) {
      f16x8 z = { (_Float16)0.f, (_Float16)0.f, (_Float16)0.f, (_Float16)0.f,
                  (_Float16)0.f, (_Float16)0.f, (_Float16)0.f, (_Float16)0.f };
      af[c] = z;
    }
  }

  float bR = 0.f, bZ = 0.f, bN = 0.f, biR = 0.f, biZ = 0.f, biN = 0.f;
  if (role == 0) {
    bR = bhh0[j_out]; bZ = bhh0[HID + j_out]; bN = bhh0[2 * HID + j_out];
  } else if (role == 2) {
    bR = bhh1[j_out]; bZ = bhh1[HID + j_out]; bN = bhh1[2 * HID + j_out];
    biR = bih1[j_out]; biZ = bih1[HID + j_out]; biN = bih1[2 * HID + j_out];
  }

  const int bfragOff = b_out * 2048 + koct * 16;

  for (int s = 0; s <= T_SEQ + 1; ++s) {
    float pre_ir = 0.f, pre_iz = 0.f, pre_in = 0.f;
    if (role == 0 && s < T_SEQ) {
      const float* gib = gi0 + (size_t)(s * NBATCH + b_out) * 3072 + j_out;
      pre_ir = gib[0]; pre_iz = gib[HID]; pre_in = gib[2 * HID];
    }

    if (w == 0) {
      unsigned need0 = (s >= 1 && s <= T_SEQ) ? (unsigned)s : 0u;       // ys0f[s-1]
      unsigned need1 = (s >= 3) ? (unsigned)(s - 2) : 0u;               // ys1f[s-3]
      if ((need0 | need1) != 0u) {
        const unsigned* f0 = flg0 + l * 4;
        const unsigned* f1 = flg1 + l * 4;
        for (;;) {
          unsigned m0 = 0xffffffffu, m1 = 0xffffffffu;
          if (need0) {
            unsigned a0 = __hip_atomic_load(f0 + 0, __ATOMIC_RELAXED, __HIP_MEMORY_SCOPE_AGENT);
            unsigned a1 = __hip_atomic_load(f0 + 1, __ATOMIC_RELAXED, __HIP_MEMORY_SCOPE_AGENT);
            unsigned a2 = __hip_atomic_load(f0 + 2, __ATOMIC_RELAXED, __HIP_MEMORY_SCOPE_AGENT);
            unsigned a3 = __hip_atomic_load(f0 + 3, __ATOMIC_RELAXED, __HIP_MEMORY_SCOPE_AGENT);
            m0 = umin4(a0, a1, a2, a3);
          }
          if (need1) {
            unsigned a0 = __hip_atomic_load(f1 + 0, __ATOMIC_RELAXED, __HIP_MEMORY_SCOPE_AGENT);
            unsigned a1 = __hip_atomic_load(f1 + 1, __ATOMIC_RELAXED, __HIP_MEMORY_SCOPE_AGENT);
            unsigned a2 = __hip_atomic_load(f1 + 2, __ATOMIC_RELAXED, __HIP_MEMORY_SCOPE_AGENT);
            unsigned a3 = __hip_atomic_load(f1 + 3, __ATOMIC_RELAXED, __HIP_MEMORY_SCOPE_AGENT);
            m1 = umin4(a0, a1, a2, a3);
          }
          if (__all(m0 >= need0 && m1 >= need1)) break;
          __builtin_amdgcn_s_sleep(1);
        }
        asm volatile("" ::: "memory");
      }
    }
    __syncthreads();

    // ---------- role 0: layer-0 step t = s ----------
    if (role == 0 && s < T_SEQ) {
      const _Float16* hsrc = (s == 0) ? h0i : (ys0f + (size_t)(s - 1) * NBATCH * HID);
      const char* hb = (const char*)hsrc + bfragOff;
      f32x4 acc0 = {}, acc1 = {};
#pragma unroll
      for (int c = 0; c < 32; c += 2) {
        f16x8 bf0 = *(const f16x8*)(hb + c * 64);
        f16x8 bf1 = *(const f16x8*)(hb + c * 64 + 64);
        acc0 = __builtin_amdgcn_mfma_f32_16x16x32_f16(af[c], bf0, acc0, 0, 0, 0);
        acc1 = __builtin_amdgcn_mfma_f32_16x16x32_f16(af[c + 1], bf1, acc1, 0, 0, 0);
      }
      f32x4 acc = acc0 + acc1;

      float hp = (float)((s == 0) ? h0i[b_out * HID + j_out]
                                  : ys0f[(size_t)((s - 1) * NBATCH + b_out) * HID + j_out]);
      float r = sigm(pre_ir + acc[0] + bR);
      float z = sigm(pre_iz + acc[1] + bZ);
      float n = tanh_fast(pre_in + r * (acc[2] + bN));
      float hnew = (1.0f - z) * n + z * hp;

      unsigned bits = (unsigned)f2h(hnew);
      unsigned hi = __shfl_down(bits, 16);
      if (jj_even) {
        unsigned packed = (bits & 0xffffu) | (hi << 16);
        __hip_atomic_store((unsigned*)(ys0f + (size_t)(s * NBATCH + b_out) * HID + j_out),
                           packed, __ATOMIC_RELAXED, __HIP_MEMORY_SCOPE_AGENT);
      }
      // EARLY publish: own stores at coherence point, then pair handshake via LDS
      asm volatile("s_waitcnt vmcnt(0)" ::: "memory");
      if (l == 0) {
        unsigned old = atomicAdd(&cnt0, 1u);
        if (old & 1u)   // second role-0 wave to arrive this iteration
          __hip_atomic_store(&flg0[bid], (unsigned)(s + 1),
                             __ATOMIC_RELAXED, __HIP_MEMORY_SCOPE_AGENT);
      }
    }

    // ---------- role 1: layer-1 input gates for t1 = s-1 -> bufIH[s&1] ----------
    if (role == 1 && s >= 1 && s <= T_SEQ) {
      const _Float16* hsrc = ys0f + (size_t)(s - 1) * NBATCH * HID;
      const char* hb = (const char*)hsrc + bfragOff;
      f32x4 acc0 = {}, acc1 = {};
#pragma unroll
      for (int c = 0; c < 32; c += 2) {
        f16x8 bf0 = *(const f16x8*)(hb + c * 64);
        f16x8 bf1 = *(const f16x8*)(hb + c * 64 + 64);
        acc0 = __builtin_amdgcn_mfma_f32_16x16x32_f16(af[c], bf0, acc0, 0, 0, 0);
        acc1 = __builtin_amdgcn_mfma_f32_16x16x32_f16(af[c + 1], bf1, acc1, 0, 0, 0);
      }
      f32x4 acc = acc0 + acc1;
      bufIH[s & 1][0][nt][l] = acc[0];
      bufIH[s & 1][1][nt][l] = acc[1];
      bufIH[s & 1][2][nt][l] = acc[2];
    }

    // ---------- role 2: layer-1 hidden + combine for t1 = s-2 ----------
    if (role == 2 && s >= 2) {
      const int t1 = s - 2;
      const _Float16* hsrc = (t1 == 0) ? h1i : (ys1f + (size_t)(t1 - 1) * NBATCH * HID);
      const char* hb = (const char*)hsrc + bfragOff;
      f32x4 acc0 = {}, acc1 = {};
#pragma unroll
      for (int c = 0; c < 32; c += 2) {
        f16x8 bf0 = *(const f16x8*)(hb + c * 64);
        f16x8 bf1 = *(const f16x8*)(hb + c * 64 + 64);
        acc0 = __builtin_amdgcn_mfma_f32_16x16x32_f16(af[c], bf0, acc0, 0, 0, 0);
        acc1 = __builtin_amdgcn_mfma_f32_16x16x32_f16(af[c + 1], bf1, acc1, 0, 0, 0);
      }
      f32x4 acc = acc0 + acc1;

      const int par = (s - 1) & 1;
      float ihR = bufIH[par][0][nt][l] + biR;
      float ihZ = bufIH[par][1][nt][l] + biZ;
      float ihN = bufIH[par][2][nt][l] + biN;
      float hp = (float)((t1 == 0) ? h1i[b_out * HID + j_out]
                                   : ys1f[(size_t)((t1 - 1) * NBATCH + b_out) * HID + j_out]);
      float r = sigm(ihR + acc[0] + bR);
      float z = sigm(ihZ + acc[1] + bZ);
      float n = tanh_fast(ihN + r * (acc[2] + bN));
      float hnew = (1.0f - z) * n + z * hp;

      unsigned bits = (unsigned)f2h(hnew);
      unsigned hi = __shfl_down(bits, 16);
      if (jj_even) {
        unsigned packed = (bits & 0xffffu) | (hi << 16);
        __hip_atomic_store((unsigned*)(ys1f + (size_t)(t1 * NBATCH + b_out) * HID + j_out),
                           packed, __ATOMIC_RELAXED, __HIP_MEMORY_SCOPE_AGENT);
      }
      asm volatile("s_waitcnt vmcnt(0)" ::: "memory");
      if (l == 0) {
        unsigned old = atomicAdd(&cnt1, 1u);
        if (old & 1u)   // second role-2 wave to arrive this iteration
          __hip_atomic_store(&flg1[bid], (unsigned)(s - 1),
                             __ATOMIC_RELAXED, __HIP_MEMORY_SCOPE_AGENT);
      }
    }

    __syncthreads();   // bufIH parity ordering + loop alignment (publishes already done)
  }
}

// ---------------- host ----------------
extern "C" void kernel_launch(void* const* d_in, const int* in_sizes, int n_in,
                              void* d_out, int out_size, void* d_ws, size_t ws_size,
                              hipStream_t stream)
{
  const int*   inputs = (const int*)d_in[0];
  const float* hidden = (const float*)d_in[2];
  const float* table  = (const float*)d_in[3];
  const float* Wih0   = (const float*)d_in[4];
  const float* Whh0   = (const float*)d_in[5];
  const float* bih0   = (const float*)d_in[6];
  const float* bhh0   = (const float*)d_in[7];
  const float* Wih1   = (const float*)d_in[8];
  const float* Whh1   = (const float*)d_in[9];
  const float* bih1   = (const float*)d_in[10];
  const float* bhh1   = (const float*)d_in[11];
  const float* Wout   = (const float*)d_in[12];
  const float* bout   = (const float*)d_in[13];
  float* out = (float*)d_out;

  char* ws = (char*)d_ws;
  size_t off = 0;
  auto alloc = [&](size_t bytes) {
    void* p = ws + off;
    off += (bytes + 255) & ~(size_t)255;
    return p;
  };
  float*     gi0  = (float*)alloc((size_t)4096 * 3072 * 4);       // 48 MB
  _Float16*  ys0f = (_Float16*)alloc((size_t)4096 * 1024 * 2);    // 8 MB
  _Float16*  ys1f = (_Float16*)alloc((size_t)4096 * 1024 * 2);    // 8 MB
  short*     A0   = (short*)alloc((size_t)4096 * 512 * 2);
  short*     B0   = (short*)alloc((size_t)3072 * 512 * 2);
  short*     B2   = (short*)alloc((size_t)32000 * 1024 * 2);      // 64 MB
  _Float16*  hcat = (_Float16*)alloc((size_t)2 * 32 * 1024 * 2);
  _Float16*  h0i  = hcat;
  _Float16*  h1i  = hcat + 32 * 1024;
  unsigned int* flg0 = (unsigned int*)alloc(256 * 4);
  unsigned int* flg1 = (unsigned int*)alloc(256 * 4);

  // zero sync flags first (stream-ordered before the recurrence; covers flg0+flg1)
  k_zero<<<1, 512, 0, stream>>>(flg0, 512);

  // conversions
  k_f32_to_f16<<<1024, 256, 0, stream>>>((const float4*)Wih0, (ushort4*)B0, 3072 * 512 / 4);
  k_f32_to_f16<<<2048, 256, 0, stream>>>((const float4*)Wout, (ushort4*)B2, 32000 * 1024 / 4);
  k_f32_to_f16<<<64, 256, 0, stream>>>((const float4*)hidden, (ushort4*)hcat, 2 * 32 * 1024 / 4);
  k_embed<<<2048, 256, 0, stream>>>(inputs, table, (ushort4*)A0);

  // layer-0 input-side gates: gi0 = A0 @ Wih0^T + bih0   [4096,3072]  (8-phase template)
  dim3 g0(16, 12);
  k_gemm256<512, 8, false><<<g0, 512, 0, stream>>>(A0, B0, gi0, bih0, 3072);

  // fused 2-layer recurrence (grid must stay <= 256 for cooperative launch)
  {
    void* kargs[] = {
      (void*)&gi0, (void*)&Whh0, (void*)&bhh0,
      (void*)&Wih1, (void*)&bih1, (void*)&Whh1, (void*)&bhh1,
      (void*)&h0i, (void*)&h1i, (void*)&ys0f, (void*)&ys1f,
      (void*)&flg0, (void*)&flg1
    };
    hipError_t e = hipLaunchCooperativeKernel((const void*)k_gru_fused, dim3(NBLK),
                                              dim3(384), kargs, 0, stream);
    if (e != hipSuccess) {
      (void)hipGetLastError();   // clear error state; fall back to plain launch
      k_gru_fused<<<dim3(NBLK), dim3(384), 0, stream>>>(
          gi0, Whh0, bhh0, Wih1, bih1, Whh1, bhh1,
          h0i, h1i, ys0f, ys1f, flg0, flg1);
    }
  }

  // output projection: logits[b,s,v] via 256^2 8-phase kernel
  dim3 g2(16, 125);
  k_gemm256<1024, 16, true><<<g2, 512, 0, stream>>>((const short*)ys1f, B2, out, bout, NVOCAB);
}

// Round 16
// 1473.653 us; speedup vs baseline: 1.2454x; 1.2454x over previous
//
#include <hip/hip_runtime.h>
#include <hip/hip_bf16.h>
#include <stdint.h>

#define T_SEQ 128
#define NBATCH 32
#define EMBED 512
#define HID 1024
#define NVOCAB 32000
#define NBLK 256   // recurrence worker blocks

typedef float f32x4 __attribute__((ext_vector_type(4)));
typedef _Float16 f16x8 __attribute__((ext_vector_type(8)));

__device__ __forceinline__ unsigned short f2h(float f) {
  _Float16 h = (_Float16)f;
  return __builtin_bit_cast(unsigned short, h);
}
__device__ __forceinline__ float sigm(float x) {
  return 1.0f / (1.0f + __expf(-x));
}
__device__ __forceinline__ float tanh_fast(float x) {
  return 2.0f / (1.0f + __expf(-2.0f * x)) - 1.0f;
}
__device__ __forceinline__ unsigned umin4(unsigned a, unsigned b, unsigned c, unsigned d) {
  unsigned x = a < b ? a : b;
  unsigned y = c < d ? c : d;
  return x < y ? x : y;
}

// ---------------- zero the sync flags (512 uints) ----------------
__global__ void k_zero(unsigned int* __restrict__ p, int n) {
  int i = blockIdx.x * blockDim.x + threadIdx.x;
  if (i < n) p[i] = 0;
}

// ---------------- f32 -> f16 convert (vectorized, grid-stride) ----------------
__global__ void k_f32_to_f16(const float4* __restrict__ in,
                             ushort4* __restrict__ out, int n4) {
  int i = blockIdx.x * blockDim.x + threadIdx.x;
  int stride = gridDim.x * blockDim.x;
  for (; i < n4; i += stride) {
    float4 v = in[i];
    ushort4 o;
    o.x = f2h(v.x); o.y = f2h(v.y); o.z = f2h(v.z); o.w = f2h(v.w);
    out[i] = o;
  }
}

// ------------- embedding gather -> A0 f16 [4096][512], row m = t*32+b -------------
__global__ void k_embed(const int* __restrict__ tok, const float* __restrict__ table,
                        ushort4* __restrict__ A0) {
  int tid = blockIdx.x * 256 + threadIdx.x;   // 4096*128 threads total
  int m = tid >> 7, kq = tid & 127;
  int b = m & 31, t = m >> 5;
  int tk = tok[b * T_SEQ + t];
  float4 v = *(const float4*)(table + (size_t)tk * EMBED + kq * 4);
  ushort4 o;
  o.x = f2h(v.x); o.y = f2h(v.y); o.z = f2h(v.z); o.w = f2h(v.w);
  A0[tid] = o;
}

// ============ 256^2 8-phase f16 GEMM template: C = A[M,K] x B[N,K]^T (+bias) ============
// Round-11 proven structure. Templated on LK (=K), GNT (=K/64), PERM (logits row perm).
template<int LKv, int GNTv, bool PERM>
__global__ __launch_bounds__(512, 2) void k_gemm256(
    const short* __restrict__ A,    // [M][LKv] f16
    const short* __restrict__ B,    // [N][LKv] f16
    float* __restrict__ C,          // [M][N] f32
    const float* __restrict__ bias, // [N]
    int N)                          // C stride
{
  __shared__ __align__(16) short As[2][256 * 64];   // 64 KB
  __shared__ __align__(16) short Bs[2][256 * 64];   // 64 KB

  const int tid = threadIdx.x;
  const int l = tid & 63, wid = tid >> 6;
  const int wm = wid >> 2, wn = wid & 3;
  const int l15 = l & 15, lkg = l >> 4;
  const int bm = blockIdx.x * 256, bn = blockIdx.y * 256;

  f32x4 acc[8][4] = {};

  auto stage_half = [&](int kt, int op, int half) {
    const short* G = op ? B : A;
    const int base_row = (op ? bn : bm) + half * 128;
    char* L = (char*)(op ? Bs[kt & 1] : As[kt & 1]) + half * 128 * 64 * 2;
#pragma unroll
    for (int p = 0; p < 2; ++p) {
      int chunk = p * 512 + tid;           // 16B chunk in half-tile
      int Lbyte = chunk * 16;
      int r = Lbyte >> 7;                  // row (128B per row)
      int cb = Lbyte & 127;
      int scb = cb ^ ((r & 7) << 4);       // swizzled source col-byte (involution)
      const char* src = (const char*)&G[(size_t)(base_row + r) * LKv + kt * 64] + scb;
      char* dst = L + (p * 512 + wid * 64) * 16;   // wave-uniform; HW adds lane*16
      __builtin_amdgcn_global_load_lds(
          (const __attribute__((address_space(1))) void*)src,
          (__attribute__((address_space(3))) void*)dst, 16, 0, 0);
    }
  };

  // ---- prologue: stage A(t0), B(t0), A(t1); allow A(t1) in flight ----
  stage_half(0, 0, 0); stage_half(0, 0, 1);
  stage_half(0, 1, 0); stage_half(0, 1, 1);
  stage_half(1, 0, 0); stage_half(1, 0, 1);
  asm volatile("s_waitcnt vmcnt(4)" ::: "memory");
  __builtin_amdgcn_sched_barrier(0);
  __builtin_amdgcn_s_barrier();
  __builtin_amdgcn_sched_barrier(0);

  for (int kt = 0; kt < GNTv; ++kt) {
    const char* bufA = (const char*)As[kt & 1];
    const char* bufB = (const char*)Bs[kt & 1];
    f16x8 afr[8][2];
    f16x8 bfr[2][2];

#define RD_A(mi_, ks_) \
    (*(const f16x8*)(bufA + ((wm * 128 + (mi_) * 16 + l15) * 128 + \
        (((ks_) * 64 + lkg * 16) ^ (((wm * 128 + (mi_) * 16 + l15) & 7) << 4)))))
#define RD_B(ni_, ks_) \
    (*(const f16x8*)(bufB + ((wn * 64 + (ni_) * 16 + l15) * 128 + \
        (((ks_) * 64 + lkg * 16) ^ (((wn * 64 + (ni_) * 16 + l15) & 7) << 4)))))

#define MFMA_QUAD(MI0, NI0) \
    __builtin_amdgcn_s_setprio(1); \
    _Pragma("unroll") \
    for (int ks = 0; ks < 2; ++ks) \
      _Pragma("unroll") \
      for (int i = 0; i < 4; ++i) \
        _Pragma("unroll") \
        for (int j = 0; j < 2; ++j) \
          acc[(MI0) + i][(NI0) + j] = __builtin_amdgcn_mfma_f32_16x16x32_f16( \
              afr[(MI0) + i][ks], bfr[j][ks], acc[(MI0) + i][(NI0) + j], 0, 0, 0); \
    __builtin_amdgcn_s_setprio(0);

#define PHASE_BARS() \
    __builtin_amdgcn_s_barrier(); __builtin_amdgcn_sched_barrier(0);

    // ---- q0: read A(mi0-3) + B(ni0-1); stage B(kt+1, half0); MFMA quad (0,0) ----
#pragma unroll
    for (int i = 0; i < 4; ++i) { afr[i][0] = RD_A(i, 0); afr[i][1] = RD_A(i, 1); }
#pragma unroll
    for (int j = 0; j < 2; ++j) { bfr[j][0] = RD_B(j, 0); bfr[j][1] = RD_B(j, 1); }
    if (kt + 1 < GNTv) stage_half(kt + 1, 1, 0);
    PHASE_BARS();
    MFMA_QUAD(0, 0);
    PHASE_BARS();

    // ---- q1: read A(mi4-7); stage B(kt+1, half1); MFMA quad (4,0) ----
#pragma unroll
    for (int i = 0; i < 4; ++i) { afr[4 + i][0] = RD_A(4 + i, 0); afr[4 + i][1] = RD_A(4 + i, 1); }
    if (kt + 1 < GNTv) stage_half(kt + 1, 1, 1);
    PHASE_BARS();
    MFMA_QUAD(4, 0);
    PHASE_BARS();

    // ---- q2: read B(ni2-3); stage A(kt+2, half0); MFMA quad (0,2) ----
    // (safe: all A-reads of tile kt completed before q1's barrier)
#pragma unroll
    for (int j = 0; j < 2; ++j) { bfr[j][0] = RD_B(2 + j, 0); bfr[j][1] = RD_B(2 + j, 1); }
    if (kt + 2 < GNTv) stage_half(kt + 2, 0, 0);
    PHASE_BARS();
    MFMA_QUAD(0, 2);
    PHASE_BARS();

    // ---- q3: stage A(kt+2, half1); MFMA quad (4,2) ----
    if (kt + 2 < GNTv) stage_half(kt + 2, 0, 1);
    PHASE_BARS();
    MFMA_QUAD(4, 2);
    PHASE_BARS();

    // ---- tile boundary: counted vmcnt (A(kt+2) halves may stay in flight) ----
    if (kt + 1 < GNTv) {
      if (kt + 2 < GNTv) {
        asm volatile("s_waitcnt vmcnt(4)" ::: "memory");
      } else {
        asm volatile("s_waitcnt vmcnt(0)" ::: "memory");
      }
      __builtin_amdgcn_sched_barrier(0);
      __builtin_amdgcn_s_barrier();
      __builtin_amdgcn_sched_barrier(0);
    }
#undef RD_A
#undef RD_B
#undef MFMA_QUAD
#undef PHASE_BARS
  }

  // ---- epilogue: (optionally permuted) rows + bias ----
  const int lr = lkg * 4;
#pragma unroll
  for (int mi = 0; mi < 8; ++mi) {
#pragma unroll
    for (int ni = 0; ni < 4; ++ni) {
      int col = bn + wn * 64 + ni * 16 + l15;
      float bv = bias[col];
#pragma unroll
      for (int j = 0; j < 4; ++j) {
        int row = bm + wm * 128 + mi * 16 + lr + j;
        int orow = PERM ? ((row & 31) * T_SEQ + (row >> 5)) : row;
        C[(size_t)orow * N + col] = acc[mi][ni][j] + bv;
      }
    }
  }
}

// ---------------- fused 2-layer GRU recurrence (round-4 EXACT: measured floor, 8 variants bracketed) ----------------
__global__ __launch_bounds__(384, 2) void k_gru_fused(
    const float* __restrict__ gi0,    // [128][32][3072] (includes b_ih0)
    const float* __restrict__ Whh0,   // [3072][1024]
    const float* __restrict__ bhh0,   // [3072]
    const float* __restrict__ Wih1,   // [3072][1024]
    const float* __restrict__ bih1,   // [3072]
    const float* __restrict__ Whh1,   // [3072][1024]
    const float* __restrict__ bhh1,   // [3072]
    const _Float16* __restrict__ h0i, // [32][1024]
    const _Float16* __restrict__ h1i, // [32][1024]
    _Float16* __restrict__ ys0f,      // [128][32][1024]
    _Float16* __restrict__ ys1f,      // [128][32][1024]
    unsigned int* flg0,               // [256]
    unsigned int* flg1)               // [256]
{
  __shared__ float bufIH[2][3][2][64];  // [parity][gate][nt][lane]

  const int tid = threadIdx.x;
  const int l = tid & 63;
  const int w = tid >> 6;
  const int role = w >> 1, nt = w & 1;
  const int bid = blockIdx.x;
  const int j0 = bid * 4;

  const int row16 = l & 15;
  const int jjr = row16 >> 2, gate = row16 & 3;
  const int koct = l >> 4;

  const int b_out = nt * 16 + (l & 15);
  const int j_out = j0 + (l >> 4);
  const int jj_even = (((l >> 4) & 1) == 0);

  const float* Wsrc = (role == 0) ? Whh0 : ((role == 1) ? Wih1 : Whh1);
  f16x8 af[32];
  if (gate < 3) {
    const float* wrow = Wsrc + (size_t)(gate * HID + j0 + jjr) * HID;
#pragma unroll
    for (int c = 0; c < 32; ++c) {
      float4 p0 = *(const float4*)(wrow + c * 32 + koct * 8);
      float4 p1 = *(const float4*)(wrow + c * 32 + koct * 8 + 4);
      f16x8 v = { (_Float16)p0.x, (_Float16)p0.y, (_Float16)p0.z, (_Float16)p0.w,
                  (_Float16)p1.x, (_Float16)p1.y, (_Float16)p1.z, (_Float16)p1.w };
      af[c] = v;
    }
  } else {
#pragma unroll
    for (int c = 0; c < 32; ++c) {
      f16x8 z = { (_Float16)0.f, (_Float16)0.f, (_Float16)0.f, (_Float16)0.f,
                  (_Float16)0.f, (_Float16)0.f, (_Float16)0.f, (_Float16)0.f };
      af[c] = z;
    }
  }

  float bR = 0.f, bZ = 0.f, bN = 0.f, biR = 0.f, biZ = 0.f, biN = 0.f;
  if (role == 0) {
    bR = bhh0[j_out]; bZ = bhh0[HID + j_out]; bN = bhh0[2 * HID + j_out];
  } else if (role == 2) {
    bR = bhh1[j_out]; bZ = bhh1[HID + j_out]; bN = bhh1[2 * HID + j_out];
    biR = bih1[j_out]; biZ = bih1[HID + j_out]; biN = bih1[2 * HID + j_out];
  }

  const int bfragOff = b_out * 2048 + koct * 16;

  for (int s = 0; s <= T_SEQ + 1; ++s) {
    float pre_ir = 0.f, pre_iz = 0.f, pre_in = 0.f;
    if (role == 0 && s < T_SEQ) {
      const float* gib = gi0 + (size_t)(s * NBATCH + b_out) * 3072 + j_out;
      pre_ir = gib[0]; pre_iz = gib[HID]; pre_in = gib[2 * HID];
    }

    if (w == 0) {
      unsigned need0 = (s >= 1 && s <= T_SEQ) ? (unsigned)s : 0u;       // ys0f[s-1]
      unsigned need1 = (s >= 3) ? (unsigned)(s - 2) : 0u;               // ys1f[s-3]
      if ((need0 | need1) != 0u) {
        const unsigned* f0 = flg0 + l * 4;
        const unsigned* f1 = flg1 + l * 4;
        for (;;) {
          unsigned m0 = 0xffffffffu, m1 = 0xffffffffu;
          if (need0) {
            unsigned a0 = __hip_atomic_load(f0 + 0, __ATOMIC_RELAXED, __HIP_MEMORY_SCOPE_AGENT);
            unsigned a1 = __hip_atomic_load(f0 + 1, __ATOMIC_RELAXED, __HIP_MEMORY_SCOPE_AGENT);
            unsigned a2 = __hip_atomic_load(f0 + 2, __ATOMIC_RELAXED, __HIP_MEMORY_SCOPE_AGENT);
            unsigned a3 = __hip_atomic_load(f0 + 3, __ATOMIC_RELAXED, __HIP_MEMORY_SCOPE_AGENT);
            m0 = umin4(a0, a1, a2, a3);
          }
          if (need1) {
            unsigned a0 = __hip_atomic_load(f1 + 0, __ATOMIC_RELAXED, __HIP_MEMORY_SCOPE_AGENT);
            unsigned a1 = __hip_atomic_load(f1 + 1, __ATOMIC_RELAXED, __HIP_MEMORY_SCOPE_AGENT);
            unsigned a2 = __hip_atomic_load(f1 + 2, __ATOMIC_RELAXED, __HIP_MEMORY_SCOPE_AGENT);
            unsigned a3 = __hip_atomic_load(f1 + 3, __ATOMIC_RELAXED, __HIP_MEMORY_SCOPE_AGENT);
            m1 = umin4(a0, a1, a2, a3);
          }
          if (__all(m0 >= need0 && m1 >= need1)) break;
          __builtin_amdgcn_s_sleep(1);
        }
        asm volatile("" ::: "memory");
      }
    }
    __syncthreads();

    // ---------- role 0: layer-0 step t = s ----------
    if (role == 0 && s < T_SEQ) {
      const _Float16* hsrc = (s == 0) ? h0i : (ys0f + (size_t)(s - 1) * NBATCH * HID);
      const char* hb = (const char*)hsrc + bfragOff;
      f32x4 acc0 = {}, acc1 = {};
#pragma unroll
      for (int c = 0; c < 32; c += 2) {
        f16x8 bf0 = *(const f16x8*)(hb + c * 64);
        f16x8 bf1 = *(const f16x8*)(hb + c * 64 + 64);
        acc0 = __builtin_amdgcn_mfma_f32_16x16x32_f16(af[c], bf0, acc0, 0, 0, 0);
        acc1 = __builtin_amdgcn_mfma_f32_16x16x32_f16(af[c + 1], bf1, acc1, 0, 0, 0);
      }
      f32x4 acc = acc0 + acc1;

      float hp = (float)((s == 0) ? h0i[b_out * HID + j_out]
                                  : ys0f[(size_t)((s - 1) * NBATCH + b_out) * HID + j_out]);
      float r = sigm(pre_ir + acc[0] + bR);
      float z = sigm(pre_iz + acc[1] + bZ);
      float n = tanh_fast(pre_in + r * (acc[2] + bN));
      float hnew = (1.0f - z) * n + z * hp;

      unsigned bits = (unsigned)f2h(hnew);
      unsigned hi = __shfl_down(bits, 16);
      if (jj_even) {
        unsigned packed = (bits & 0xffffu) | (hi << 16);
        __hip_atomic_store((unsigned*)(ys0f + (size_t)(s * NBATCH + b_out) * HID + j_out),
                           packed, __ATOMIC_RELAXED, __HIP_MEMORY_SCOPE_AGENT);
      }
    }

    // ---------- role 1: layer-1 input gates for t1 = s-1 -> bufIH[s&1] ----------
    if (role == 1 && s >= 1 && s <= T_SEQ) {
      const _Float16* hsrc = ys0f + (size_t)(s - 1) * NBATCH * HID;
      const char* hb = (const char*)hsrc + bfragOff;
      f32x4 acc0 = {}, acc1 = {};
#pragma unroll
      for (int c = 0; c < 32; c += 2) {
        f16x8 bf0 = *(const f16x8*)(hb + c * 64);
        f16x8 bf1 = *(const f16x8*)(hb + c * 64 + 64);
        acc0 = __builtin_amdgcn_mfma_f32_16x16x32_f16(af[c], bf0, acc0, 0, 0, 0);
        acc1 = __builtin_amdgcn_mfma_f32_16x16x32_f16(af[c + 1], bf1, acc1, 0, 0, 0);
      }
      f32x4 acc = acc0 + acc1;
      bufIH[s & 1][0][nt][l] = acc[0];
      bufIH[s & 1][1][nt][l] = acc[1];
      bufIH[s & 1][2][nt][l] = acc[2];
    }

    // ---------- role 2: layer-1 hidden + combine for t1 = s-2 ----------
    if (role == 2 && s >= 2) {
      const int t1 = s - 2;
      const _Float16* hsrc = (t1 == 0) ? h1i : (ys1f + (size_t)(t1 - 1) * NBATCH * HID);
      const char* hb = (const char*)hsrc + bfragOff;
      f32x4 acc0 = {}, acc1 = {};
#pragma unroll
      for (int c = 0; c < 32; c += 2) {
        f16x8 bf0 = *(const f16x8*)(hb + c * 64);
        f16x8 bf1 = *(const f16x8*)(hb + c * 64 + 64);
        acc0 = __builtin_amdgcn_mfma_f32_16x16x32_f16(af[c], bf0, acc0, 0, 0, 0);
        acc1 = __builtin_amdgcn_mfma_f32_16x16x32_f16(af[c + 1], bf1, acc1, 0, 0, 0);
      }
      f32x4 acc = acc0 + acc1;

      const int par = (s - 1) & 1;
      float ihR = bufIH[par][0][nt][l] + biR;
      float ihZ = bufIH[par][1][nt][l] + biZ;
      float ihN = bufIH[par][2][nt][l] + biN;
      float hp = (float)((t1 == 0) ? h1i[b_out * HID + j_out]
                                   : ys1f[(size_t)((t1 - 1) * NBATCH + b_out) * HID + j_out]);
      float r = sigm(ihR + acc[0] + bR);
      float z = sigm(ihZ + acc[1] + bZ);
      float n = tanh_fast(ihN + r * (acc[2] + bN));
      float hnew = (1.0f - z) * n + z * hp;

      unsigned bits = (unsigned)f2h(hnew);
      unsigned hi = __shfl_down(bits, 16);
      if (jj_even) {
        unsigned packed = (bits & 0xffffu) | (hi << 16);
        __hip_atomic_store((unsigned*)(ys1f + (size_t)(t1 * NBATCH + b_out) * HID + j_out),
                           packed, __ATOMIC_RELAXED, __HIP_MEMORY_SCOPE_AGENT);
      }
    }

    __syncthreads();   // drains each wave's stores (vmcnt 0) + publishes bufIH

    if (tid == 0) {
      if (s < T_SEQ)
        __hip_atomic_store(&flg0[bid], (unsigned)(s + 1), __ATOMIC_RELAXED, __HIP_MEMORY_SCOPE_AGENT);
      if (s >= 2)
        __hip_atomic_store(&flg1[bid], (unsigned)(s - 1), __ATOMIC_RELAXED, __HIP_MEMORY_SCOPE_AGENT);
    }
  }
}

// ---------------- host ----------------
extern "C" void kernel_launch(void* const* d_in, const int* in_sizes, int n_in,
                              void* d_out, int out_size, void* d_ws, size_t ws_size,
                              hipStream_t stream)
{
  const int*   inputs = (const int*)d_in[0];
  const float* hidden = (const float*)d_in[2];
  const float* table  = (const float*)d_in[3];
  const float* Wih0   = (const float*)d_in[4];
  const float* Whh0   = (const float*)d_in[5];
  const float* bih0   = (const float*)d_in[6];
  const float* bhh0   = (const float*)d_in[7];
  const float* Wih1   = (const float*)d_in[8];
  const float* Whh1   = (const float*)d_in[9];
  const float* bih1   = (const float*)d_in[10];
  const float* bhh1   = (const float*)d_in[11];
  const float* Wout   = (const float*)d_in[12];
  const float* bout   = (const float*)d_in[13];
  float* out = (float*)d_out;

  char* ws = (char*)d_ws;
  size_t off = 0;
  auto alloc = [&](size_t bytes) {
    void* p = ws + off;
    off += (bytes + 255) & ~(size_t)255;
    return p;
  };
  float*     gi0  = (float*)alloc((size_t)4096 * 3072 * 4);       // 48 MB
  _Float16*  ys0f = (_Float16*)alloc((size_t)4096 * 1024 * 2);    // 8 MB
  _Float16*  ys1f = (_Float16*)alloc((size_t)4096 * 1024 * 2);    // 8 MB
  short*     A0   = (short*)alloc((size_t)4096 * 512 * 2);
  short*     B0   = (short*)alloc((size_t)3072 * 512 * 2);
  short*     B2   = (short*)alloc((size_t)32000 * 1024 * 2);      // 64 MB
  _Float16*  hcat = (_Float16*)alloc((size_t)2 * 32 * 1024 * 2);
  _Float16*  h0i  = hcat;
  _Float16*  h1i  = hcat + 32 * 1024;
  unsigned int* flg0 = (unsigned int*)alloc(256 * 4);
  unsigned int* flg1 = (unsigned int*)alloc(256 * 4);

  // zero sync flags first (stream-ordered before the recurrence; covers flg0+flg1)
  k_zero<<<1, 512, 0, stream>>>(flg0, 512);

  // conversions
  k_f32_to_f16<<<1024, 256, 0, stream>>>((const float4*)Wih0, (ushort4*)B0, 3072 * 512 / 4);
  k_f32_to_f16<<<2048, 256, 0, stream>>>((const float4*)Wout, (ushort4*)B2, 32000 * 1024 / 4);
  k_f32_to_f16<<<64, 256, 0, stream>>>((const float4*)hidden, (ushort4*)hcat, 2 * 32 * 1024 / 4);
  k_embed<<<2048, 256, 0, stream>>>(inputs, table, (ushort4*)A0);

  // layer-0 input-side gates: gi0 = A0 @ Wih0^T + bih0   [4096,3072]  (8-phase template)
  dim3 g0(16, 12);
  k_gemm256<512, 8, false><<<g0, 512, 0, stream>>>(A0, B0, gi0, bih0, 3072);

  // fused 2-layer recurrence (round-4-exact protocol; grid must stay <= 256)
  {
    void* kargs[] = {
      (void*)&gi0, (void*)&Whh0, (void*)&bhh0,
      (void*)&Wih1, (void*)&bih1, (void*)&Whh1, (void*)&bhh1,
      (void*)&h0i, (void*)&h1i, (void*)&ys0f, (void*)&ys1f,
      (void*)&flg0, (void*)&flg1
    };
    hipError_t e = hipLaunchCooperativeKernel((const void*)k_gru_fused, dim3(NBLK),
                                              dim3(384), kargs, 0, stream);
    if (e != hipSuccess) {
      (void)hipGetLastError();   // clear error state; fall back to plain launch
      k_gru_fused<<<dim3(NBLK), dim3(384), 0, stream>>>(
          gi0, Whh0, bhh0, Wih1, bih1, Whh1, bhh1,
          h0i, h1i, ys0f, ys1f, flg0, flg1);
    }
  }

  // output projection: logits[b,s,v] via 256^2 8-phase kernel
  dim3 g2(16, 125);
  k_gemm256<1024, 16, true><<<g2, 512, 0, stream>>>((const short*)ys1f, B2, out, bout, NVOCAB);
}